// Round 12
// baseline (1131.575 us; speedup 1.0000x reference)
//
#include <hip/hip_runtime.h>
#include <hip/hip_bf16.h>

#define DIM 128
#define CHUNK 8192
typedef __hip_bfloat16 bf16;
typedef __attribute__((ext_vector_type(8))) short bf16x8;   // 8 bf16 = 4 VGPRs
typedef __attribute__((ext_vector_type(4))) float f32x4;

struct MArgs {
    const float* x; const int* ei;
    const float* W1; const float* b1; const float* W2; const float* b2;
    float4* out;
    int N, E, nbuck, nchunks;
    int* misc;          // [0]=bar_cnt [1]=bar_gen [2]=flagI
    int* bcnt; int* bstart; int* bcursor;
    unsigned* staged; int* csr; int* rowstart; int* cnt; float* dis;
    bf16* ybuf; bf16* hbuf; bf16* Wsw1; bf16* Wsw2;
};

// ---------------- device-scope grid barrier (persistent kernel) -------------
__device__ __forceinline__ void grid_barrier(int* cnt, int* gen) {
    __syncthreads();
    if (threadIdx.x == 0) {
        __threadfence();                                       // agent release
        int g = __hip_atomic_load(gen, __ATOMIC_RELAXED, __HIP_MEMORY_SCOPE_AGENT);
        int old = __hip_atomic_fetch_add(cnt, 1, __ATOMIC_ACQ_REL, __HIP_MEMORY_SCOPE_AGENT);
        if (old == (int)gridDim.x - 1) {
            __hip_atomic_store(cnt, 0, __ATOMIC_RELAXED, __HIP_MEMORY_SCOPE_AGENT);
            __hip_atomic_fetch_add(gen, 1, __ATOMIC_RELEASE, __HIP_MEMORY_SCOPE_AGENT);
        } else {
            long t = 0;
            while (__hip_atomic_load(gen, __ATOMIC_ACQUIRE, __HIP_MEMORY_SCOPE_AGENT) == g) {
                __builtin_amdgcn_s_sleep(2);
                if (++t > 2000000) break;                      // no-hang safety
            }
        }
        __threadfence();                                       // agent acquire
    }
    __syncthreads();
}

// ---------------- MFMA gemm body: Y = bf16(X @ W) (UNSCALED) ----------------
template <bool XF32>
__device__ __forceinline__ void gemm_body(const void* __restrict__ Xv,
                                          const bf16* __restrict__ Wsw,
                                          bf16* __restrict__ Y, int N,
                                          int gw, int nw, int lane) {
    int m = lane & 15, q = lane >> 4;
    const bf16x8* bp = (const bf16x8*)Wsw;          // frag f at bp[f*64 + lane]
    for (int t = gw; t * 16 + 16 <= N; t += nw) {
        int base = t * 16;
        bf16x8 a[4];
        if (XF32) {
            const float* xp = (const float*)Xv + (size_t)(base + m) * DIM + q * 8;
            #pragma unroll
            for (int kt = 0; kt < 4; ++kt) {
                float4 v0 = *(const float4*)(xp + kt * 32);
                float4 v1 = *(const float4*)(xp + kt * 32 + 4);
                bf16 tt[8] = {__float2bfloat16(v0.x), __float2bfloat16(v0.y),
                              __float2bfloat16(v0.z), __float2bfloat16(v0.w),
                              __float2bfloat16(v1.x), __float2bfloat16(v1.y),
                              __float2bfloat16(v1.z), __float2bfloat16(v1.w)};
                a[kt] = *(const bf16x8*)tt;
            }
        } else {
            const bf16* xp = (const bf16*)Xv + (size_t)(base + m) * DIM + q * 8;
            #pragma unroll
            for (int kt = 0; kt < 4; ++kt)
                a[kt] = *(const bf16x8*)(xp + kt * 32);
        }
        f32x4 acc[8];
        #pragma unroll
        for (int nt = 0; nt < 8; ++nt) acc[nt] = (f32x4){0.f, 0.f, 0.f, 0.f};
        #pragma unroll
        for (int kt = 0; kt < 4; ++kt) {
            #pragma unroll
            for (int nt = 0; nt < 8; ++nt) {
                bf16x8 bfr = bp[(size_t)(kt * 8 + nt) * 64 + lane];
                acc[nt] = __builtin_amdgcn_mfma_f32_16x16x32_bf16(a[kt], bfr, acc[nt], 0, 0, 0);
            }
        }
        // D: row (node) = q*4 + r, col (channel) = nt*16 + m  [m89/m91-verified]
        #pragma unroll
        for (int nt = 0; nt < 8; ++nt)
            #pragma unroll
            for (int r = 0; r < 4; ++r)
                Y[(size_t)(base + q * 4 + r) * DIM + nt * 16 + m] =
                    __float2bfloat16(acc[nt][r]);
    }
}

// ---------------- aggregate body (quarter-wave, dis folded in) --------------
__device__ __forceinline__ void fma8(float* a, uint4 v, float ds) {
    a[0] = fmaf(__uint_as_float(v.x << 16), ds, a[0]);
    a[1] = fmaf(__uint_as_float(v.x & 0xffff0000u), ds, a[1]);
    a[2] = fmaf(__uint_as_float(v.y << 16), ds, a[2]);
    a[3] = fmaf(__uint_as_float(v.y & 0xffff0000u), ds, a[3]);
    a[4] = fmaf(__uint_as_float(v.z << 16), ds, a[4]);
    a[5] = fmaf(__uint_as_float(v.z & 0xffff0000u), ds, a[5]);
    a[6] = fmaf(__uint_as_float(v.w << 16), ds, a[6]);
    a[7] = fmaf(__uint_as_float(v.w & 0xffff0000u), ds, a[7]);
}

template <bool FINAL>
__device__ __forceinline__ void agg_body(const uint4* __restrict__ Y,
                                         const int* __restrict__ rowstart,
                                         const int* __restrict__ cnt,
                                         const int* __restrict__ csr,
                                         const float* __restrict__ dis,
                                         const float* __restrict__ bias,
                                         uint4* __restrict__ Hb, float4* __restrict__ Of,
                                         int N, int qw, int nq, int cl) {
    for (int node = qw; node < N; node += nq) {
        int e0 = rowstart[node], e1 = e0 + cnt[node];
        float acc[4][8];
        #pragma unroll
        for (int j = 0; j < 4; ++j)
            #pragma unroll
            for (int k = 0; k < 8; ++k) acc[j][k] = 0.f;
        float dn = dis[node];
        fma8(acc[3], Y[(size_t)node * 16 + cl], dn);        // self loop
        int e = e0;
        while (e + 8 <= e1) {
            int s[8];
            #pragma unroll
            for (int j = 0; j < 8; ++j) s[j] = csr[e + j];
            uint4 v[8]; float dv[8];
            #pragma unroll
            for (int j = 0; j < 8; ++j) { v[j] = Y[(size_t)s[j] * 16 + cl]; dv[j] = dis[s[j]]; }
            #pragma unroll
            for (int j = 0; j < 8; ++j) fma8(acc[j & 3], v[j], dv[j]);
            e += 8;
        }
        if (e + 4 <= e1) {
            int s[4];
            #pragma unroll
            for (int j = 0; j < 4; ++j) s[j] = csr[e + j];
            uint4 v[4]; float dv[4];
            #pragma unroll
            for (int j = 0; j < 4; ++j) { v[j] = Y[(size_t)s[j] * 16 + cl]; dv[j] = dis[s[j]]; }
            #pragma unroll
            for (int j = 0; j < 4; ++j) fma8(acc[j], v[j], dv[j]);
            e += 4;
        }
        for (; e < e1; ++e) {
            int s = csr[e];
            fma8(acc[0], Y[(size_t)s * 16 + cl], dis[s]);
        }
        float s8[8];
        #pragma unroll
        for (int k = 0; k < 8; ++k)
            s8[k] = (acc[0][k] + acc[1][k]) + (acc[2][k] + acc[3][k]);
        float4 b0 = ((const float4*)bias)[2 * cl];
        float4 b1 = ((const float4*)bias)[2 * cl + 1];
        float o[8];
        o[0] = fmaxf(dn * s8[0] + b0.x, 0.f);
        o[1] = fmaxf(dn * s8[1] + b0.y, 0.f);
        o[2] = fmaxf(dn * s8[2] + b0.z, 0.f);
        o[3] = fmaxf(dn * s8[3] + b0.w, 0.f);
        o[4] = fmaxf(dn * s8[4] + b1.x, 0.f);
        o[5] = fmaxf(dn * s8[5] + b1.y, 0.f);
        o[6] = fmaxf(dn * s8[6] + b1.z, 0.f);
        o[7] = fmaxf(dn * s8[7] + b1.w, 0.f);
        if (FINAL) {
            Of[(size_t)node * 32 + 2 * cl]     = make_float4(o[0], o[1], o[2], o[3]);
            Of[(size_t)node * 32 + 2 * cl + 1] = make_float4(o[4], o[5], o[6], o[7]);
        } else {
            bf16 t[8];
            #pragma unroll
            for (int k = 0; k < 8; ++k) t[k] = __float2bfloat16(o[k]);
            Hb[(size_t)node * 16 + cl] = *(const uint4*)t;
        }
    }
}

// ============================ init: barrier state ===========================
__global__ void init_kernel(int* __restrict__ misc) {
    if (threadIdx.x < 8) misc[threadIdx.x] = 0;
}

// ============================ mega kernel ===================================
__global__ __launch_bounds__(256, 4) void mega(MArgs a) {
    __shared__ int smem[1536];
    const int G = gridDim.x;
    const int tid = threadIdx.x;
    const int gtid = blockIdx.x * 256 + tid;
    const int gsize = G * 256;
    const int wid = tid >> 6, lane = tid & 63;
    int* bar_cnt = a.misc + 0;
    int* bar_gen = a.misc + 1;

    // ---- PA: zero bcnt; swizzle W (blocks 0..15); detect flagI (block 16) --
    for (int i = gtid; i <= a.nbuck; i += gsize) a.bcnt[i] = 0;
    if (gtid < 4096) {
        // W f32 -> bf16 B-frag order: frag f=kt*8+nt; lane l: n=l&15, k=(l>>4)*8+j
        const float* W = (gtid < 2048) ? a.W1 : a.W2;
        bf16* Wsw = (gtid < 2048) ? a.Wsw1 : a.Wsw2;
        int t = gtid & 2047;
        int f = t >> 6, l = t & 63;
        int kt = f >> 3, nt = f & 7;
        int q = l >> 4, m = l & 15;
        bf16 tmp[8];
        #pragma unroll
        for (int j = 0; j < 8; ++j)
            tmp[j] = __float2bfloat16(W[(size_t)(kt * 32 + q * 8 + j) * DIM + nt * 16 + m]);
        *(bf16x8*)(Wsw + (size_t)t * 8) = *(const bf16x8*)tmp;
    }
    if (blockIdx.x == 16) {
        if (tid == 0) smem[0] = 0;
        __syncthreads();
        int lim = a.E < 16384 ? a.E : 16384;
        int acc = 0;
        for (int j = tid; j < lim; j += 256) acc |= a.ei[2 * j + 1];
        if (acc) atomicOr(&smem[0], 1);
        __syncthreads();
        if (tid == 0)
            __hip_atomic_store(&a.misc[2], smem[0], __ATOMIC_RELAXED, __HIP_MEMORY_SCOPE_AGENT);
    }
    grid_barrier(bar_cnt, bar_gen);
    const int flagI = __hip_atomic_load(&a.misc[2], __ATOMIC_RELAXED, __HIP_MEMORY_SCOPE_AGENT);

    // ---- PB: bucket count (grid-stride chunks), then gemm1 (independent) ---
    for (int c = blockIdx.x; c < a.nchunks; c += G) {
        for (int i = tid; i < a.nbuck; i += 256) smem[i] = 0;
        __syncthreads();
        int c0 = c * CHUNK;
        int cn = min(a.E - c0, CHUNK);
        for (int i = tid; i < cn; i += 256) {
            int e = c0 + i;
            int d = (flagI == 0) ? a.ei[2 * a.E + 2 * e] : a.ei[a.E + e];
            atomicAdd(&smem[d >> 7], 1);
        }
        __syncthreads();
        for (int i = tid; i < a.nbuck; i += 256)
            if (smem[i]) atomicAdd(&a.bcnt[i], smem[i]);
        __syncthreads();
    }
    gemm_body<true>(a.x, a.Wsw1, a.ybuf, a.N, blockIdx.x * 4 + wid, G * 4, lane);
    grid_barrier(bar_cnt, bar_gen);

    // ---- PC: bucket scan (block 0) -----------------------------------------
    if (blockIdx.x == 0) {
        for (int i = tid; i < a.nbuck; i += 256) smem[i] = a.bcnt[i];
        __syncthreads();
        if (tid == 0) {
            int run = 0;
            for (int i = 0; i < a.nbuck; ++i) { int v = smem[i]; smem[i] = run; run += v; }
        }
        __syncthreads();
        for (int i = tid; i < a.nbuck; i += 256) {
            a.bstart[i] = smem[i];
            a.bcursor[i] = smem[i];
        }
        if (tid == 0) a.bstart[a.nbuck] = a.E;
    }
    grid_barrier(bar_cnt, bar_gen);

    // ---- PD: bucket scatter (grid-stride chunks) ---------------------------
    {
        int* s_cnt = smem; int* s_base = smem + 512; int* s_fill = smem + 1024;
        for (int c = blockIdx.x; c < a.nchunks; c += G) {
            for (int i = tid; i < a.nbuck; i += 256) { s_cnt[i] = 0; s_fill[i] = 0; }
            __syncthreads();
            int c0 = c * CHUNK;
            int cn = min(a.E - c0, CHUNK);
            for (int i = tid; i < cn; i += 256) {
                int e = c0 + i;
                int d = (flagI == 0) ? a.ei[2 * a.E + 2 * e] : a.ei[a.E + e];
                atomicAdd(&s_cnt[d >> 7], 1);
            }
            __syncthreads();
            for (int i = tid; i < a.nbuck; i += 256) {
                int cc = s_cnt[i];
                s_base[i] = cc ? atomicAdd(&a.bcursor[i], cc) : 0;
            }
            __syncthreads();
            for (int i = tid; i < cn; i += 256) {
                int e = c0 + i;
                int s, d;
                if (flagI == 0) { s = a.ei[2 * e]; d = a.ei[2 * a.E + 2 * e]; }
                else            { s = a.ei[e];     d = a.ei[a.E + e]; }
                int b = d >> 7;
                int r = atomicAdd(&s_fill[b], 1);
                a.staged[s_base[b] + r] = ((unsigned)s << 7) | (unsigned)(d & 127);
            }
            __syncthreads();
        }
    }
    grid_barrier(bar_cnt, bar_gen);

    // ---- PE: within-bucket counting sort (grid-stride buckets) -------------
    {
        int* s_cnt = smem; int* s_off = smem + 128; int* s_fill = smem + 256;
        int* s_scan = smem + 384;
        for (int b = blockIdx.x; b < a.nbuck; b += G) {
            int seg0 = a.bstart[b], seg1 = a.bstart[b + 1];
            int n = seg1 - seg0;
            if (tid < 128) { s_cnt[tid] = 0; s_fill[tid] = 0; }
            __syncthreads();
            for (int i = tid; i < n; i += 256)
                atomicAdd(&s_cnt[a.staged[seg0 + i] & 127u], 1);
            __syncthreads();
            int v = (tid < 128) ? s_cnt[tid] : 0;
            if (tid < 128) s_scan[tid] = v;
            __syncthreads();
            for (int off = 1; off < 128; off <<= 1) {
                int t = (tid < 128 && tid >= off) ? s_scan[tid - off] : 0;
                __syncthreads();
                if (tid < 128) s_scan[tid] += t;
                __syncthreads();
            }
            if (tid < 128) {
                s_off[tid] = s_scan[tid] - v;
                int node = b * 128 + tid;
                if (node < a.N) {
                    a.cnt[node] = v;
                    a.rowstart[node] = seg0 + s_off[tid];
                    a.dis[node] = rsqrtf((float)(v + 1));   // +1 self loop
                }
            }
            __syncthreads();
            for (int i = tid; i < n; i += 256) {
                unsigned p = a.staged[seg0 + i];
                int dl = p & 127u;
                int r = atomicAdd(&s_fill[dl], 1);
                a.csr[seg0 + s_off[dl] + r] = (int)(p >> 7);
            }
            __syncthreads();
        }
    }
    grid_barrier(bar_cnt, bar_gen);

    // ---- PF: aggregate 1 -> hbuf (bf16) ------------------------------------
    {
        int sub = lane >> 4, cl = lane & 15;
        int qw = (blockIdx.x * 4 + wid) * 4 + sub;
        agg_body<false>((const uint4*)a.ybuf, a.rowstart, a.cnt, a.csr, a.dis,
                        a.b1, (uint4*)a.hbuf, nullptr, a.N, qw, G * 16, cl);
    }
    grid_barrier(bar_cnt, bar_gen);

    // ---- PG: gemm2 -> ybuf --------------------------------------------------
    gemm_body<false>(a.hbuf, a.Wsw2, a.ybuf, a.N, blockIdx.x * 4 + wid, G * 4, lane);
    grid_barrier(bar_cnt, bar_gen);

    // ---- PH: aggregate 2 -> out (f32) --------------------------------------
    {
        int sub = lane >> 4, cl = lane & 15;
        int qw = (blockIdx.x * 4 + wid) * 4 + sub;
        agg_body<true>((const uint4*)a.ybuf, a.rowstart, a.cnt, a.csr, a.dis,
                       a.b2, nullptr, a.out, a.N, qw, G * 16, cl);
    }
}

// ============================ launcher ======================================
extern "C" void kernel_launch(void* const* d_in, const int* in_sizes, int n_in,
                              void* d_out, int out_size, void* d_ws, size_t ws_size,
                              hipStream_t stream) {
    MArgs a;
    a.x  = (const float*)d_in[0];
    a.ei = (const int*)d_in[1];
    a.W1 = (const float*)d_in[2];
    a.b1 = (const float*)d_in[3];
    a.W2 = (const float*)d_in[4];
    a.b2 = (const float*)d_in[5];
    a.out = (float4*)d_out;
    a.N = in_sizes[0] / DIM;        // 50000
    a.E = in_sizes[1] / 2;          // 600000
    a.nbuck = (a.N + 127) / 128;    // 391
    a.nchunks = (a.E + CHUNK - 1) / CHUNK;  // 74

    char* w = (char*)d_ws;
    size_t used = 0;
    auto carve = [&](size_t bytes) {
        char* p = w + used;
        used += (bytes + 255) & ~(size_t)255;
        return p;
    };
    a.misc     = (int*)     carve(256);
    a.bcnt     = (int*)     carve((size_t)(a.nbuck + 1) * 4);
    a.bstart   = (int*)     carve((size_t)(a.nbuck + 1) * 4);
    a.bcursor  = (int*)     carve((size_t)a.nbuck * 4);
    a.staged   = (unsigned*)carve((size_t)a.E * 4);
    a.csr      = (int*)     carve((size_t)a.E * 4);
    a.rowstart = (int*)     carve((size_t)a.N * 4);
    a.cnt      = (int*)     carve((size_t)a.N * 4);
    a.dis      = (float*)   carve((size_t)a.N * 4);
    a.ybuf     = (bf16*)    carve((size_t)a.N * DIM * 2);
    a.hbuf     = (bf16*)    carve((size_t)a.N * DIM * 2);
    a.Wsw1     = (bf16*)    carve((size_t)DIM * DIM * 2);
    a.Wsw2     = (bf16*)    carve((size_t)DIM * DIM * 2);

    // Grid sized to guaranteed co-residency (pure host queries; capture-safe,
    // deterministic -> same work every call).
    int dev = 0;
    hipGetDevice(&dev);
    int cus = 0;
    hipDeviceGetAttribute(&cus, hipDeviceAttributeMultiprocessorCount, dev);
    if (cus <= 0) cus = 256;
    int maxB = 0;
    hipOccupancyMaxActiveBlocksPerMultiprocessor(&maxB, mega, 256, 0);
    if (maxB <= 0) maxB = 1;
    long grid = (long)maxB * cus;
    if (grid > 1024) grid = 1024;
    if (grid < 64) grid = 64;

    init_kernel<<<1, 64, 0, stream>>>(a.misc);
    mega<<<(int)grid, 256, 0, stream>>>(a);
}

// Round 14
// 539.524 us; speedup vs baseline: 2.0974x; 2.0974x over previous
//
#include <hip/hip_runtime.h>
#include <hip/hip_bf16.h>

#define DIM 128
#define CHUNK 8192
typedef __hip_bfloat16 bf16;
typedef __attribute__((ext_vector_type(8))) short bf16x8;   // 8 bf16 = 4 VGPRs
typedef __attribute__((ext_vector_type(4))) float f32x4;

struct MArgs {
    const float* x; const int* ei;
    const float* W1; const float* b1; const float* W2; const float* b2;
    float4* out;
    int N, E, nbuck, nchunks;
    int* misc;          // [0]=bar_cnt [1]=bar_gen [2]=flagI
    int* bcnt; int* bstart; int* bcursor;
    unsigned* staged; int* csr; int* rowstart; int* cnt; float* dis;
    bf16* ybuf; bf16* hbuf; bf16* Wsw1; bf16* Wsw2;
};

// ---------------- device-scope grid barrier (persistent kernel) -------------
// Spin with RELAXED loads (no per-iteration L1 invalidate — R12's bug);
// exactly ONE acquire operation after exit (single buffer_inv per barrier).
__device__ __forceinline__ void grid_barrier(int* cnt, int* gen) {
    __syncthreads();
    if (threadIdx.x == 0) {
        int g = __hip_atomic_load(gen, __ATOMIC_RELAXED, __HIP_MEMORY_SCOPE_AGENT);
        // release my block's writes, then arrive
        int old = __hip_atomic_fetch_add(cnt, 1, __ATOMIC_RELEASE, __HIP_MEMORY_SCOPE_AGENT);
        if (old == (int)gridDim.x - 1) {
            // last arriver: reset and publish next generation
            __hip_atomic_store(cnt, 0, __ATOMIC_RELAXED, __HIP_MEMORY_SCOPE_AGENT);
            __hip_atomic_store(gen, g + 1, __ATOMIC_RELEASE, __HIP_MEMORY_SCOPE_AGENT);
        } else {
            long t = 0;
            while (__hip_atomic_load(gen, __ATOMIC_RELAXED, __HIP_MEMORY_SCOPE_AGENT) == g) {
                __builtin_amdgcn_s_sleep(8);
                if (++t > 400000) break;                       // no-hang safety
            }
        }
        // single acquire: makes all other blocks' writes visible
        (void)__hip_atomic_load(gen, __ATOMIC_ACQUIRE, __HIP_MEMORY_SCOPE_AGENT);
    }
    __syncthreads();
}

// ---------------- MFMA gemm body: Y = bf16(X @ W) (UNSCALED) ----------------
template <bool XF32>
__device__ __forceinline__ void gemm_body(const void* __restrict__ Xv,
                                          const bf16* __restrict__ Wsw,
                                          bf16* __restrict__ Y, int N,
                                          int gw, int nw, int lane) {
    int m = lane & 15, q = lane >> 4;
    const bf16x8* bp = (const bf16x8*)Wsw;          // frag f at bp[f*64 + lane]
    for (int t = gw; t * 16 + 16 <= N; t += nw) {
        int base = t * 16;
        bf16x8 a[4];
        if (XF32) {
            const float* xp = (const float*)Xv + (size_t)(base + m) * DIM + q * 8;
            #pragma unroll
            for (int kt = 0; kt < 4; ++kt) {
                float4 v0 = *(const float4*)(xp + kt * 32);
                float4 v1 = *(const float4*)(xp + kt * 32 + 4);
                bf16 tt[8] = {__float2bfloat16(v0.x), __float2bfloat16(v0.y),
                              __float2bfloat16(v0.z), __float2bfloat16(v0.w),
                              __float2bfloat16(v1.x), __float2bfloat16(v1.y),
                              __float2bfloat16(v1.z), __float2bfloat16(v1.w)};
                a[kt] = *(const bf16x8*)tt;
            }
        } else {
            const bf16* xp = (const bf16*)Xv + (size_t)(base + m) * DIM + q * 8;
            #pragma unroll
            for (int kt = 0; kt < 4; ++kt)
                a[kt] = *(const bf16x8*)(xp + kt * 32);
        }
        f32x4 acc[8];
        #pragma unroll
        for (int nt = 0; nt < 8; ++nt) acc[nt] = (f32x4){0.f, 0.f, 0.f, 0.f};
        #pragma unroll
        for (int kt = 0; kt < 4; ++kt) {
            #pragma unroll
            for (int nt = 0; nt < 8; ++nt) {
                bf16x8 bfr = bp[(size_t)(kt * 8 + nt) * 64 + lane];
                acc[nt] = __builtin_amdgcn_mfma_f32_16x16x32_bf16(a[kt], bfr, acc[nt], 0, 0, 0);
            }
        }
        // D: row (node) = q*4 + r, col (channel) = nt*16 + m  [m89/m91-verified]
        #pragma unroll
        for (int nt = 0; nt < 8; ++nt)
            #pragma unroll
            for (int r = 0; r < 4; ++r)
                Y[(size_t)(base + q * 4 + r) * DIM + nt * 16 + m] =
                    __float2bfloat16(acc[nt][r]);
    }
}

// ---------------- aggregate body (quarter-wave, dis folded in) --------------
__device__ __forceinline__ void fma8(float* a, uint4 v, float ds) {
    a[0] = fmaf(__uint_as_float(v.x << 16), ds, a[0]);
    a[1] = fmaf(__uint_as_float(v.x & 0xffff0000u), ds, a[1]);
    a[2] = fmaf(__uint_as_float(v.y << 16), ds, a[2]);
    a[3] = fmaf(__uint_as_float(v.y & 0xffff0000u), ds, a[3]);
    a[4] = fmaf(__uint_as_float(v.z << 16), ds, a[4]);
    a[5] = fmaf(__uint_as_float(v.z & 0xffff0000u), ds, a[5]);
    a[6] = fmaf(__uint_as_float(v.w << 16), ds, a[6]);
    a[7] = fmaf(__uint_as_float(v.w & 0xffff0000u), ds, a[7]);
}

template <bool FINAL>
__device__ __forceinline__ void agg_body(const uint4* __restrict__ Y,
                                         const int* __restrict__ rowstart,
                                         const int* __restrict__ cnt,
                                         const int* __restrict__ csr,
                                         const float* __restrict__ dis,
                                         const float* __restrict__ bias,
                                         uint4* __restrict__ Hb, float4* __restrict__ Of,
                                         int N, int qw, int nq, int cl) {
    for (int node = qw; node < N; node += nq) {
        int e0 = rowstart[node], e1 = e0 + cnt[node];
        float acc[4][8];
        #pragma unroll
        for (int j = 0; j < 4; ++j)
            #pragma unroll
            for (int k = 0; k < 8; ++k) acc[j][k] = 0.f;
        float dn = dis[node];
        fma8(acc[3], Y[(size_t)node * 16 + cl], dn);        // self loop
        int e = e0;
        while (e + 8 <= e1) {
            int s[8];
            #pragma unroll
            for (int j = 0; j < 8; ++j) s[j] = csr[e + j];
            uint4 v[8]; float dv[8];
            #pragma unroll
            for (int j = 0; j < 8; ++j) { v[j] = Y[(size_t)s[j] * 16 + cl]; dv[j] = dis[s[j]]; }
            #pragma unroll
            for (int j = 0; j < 8; ++j) fma8(acc[j & 3], v[j], dv[j]);
            e += 8;
        }
        if (e + 4 <= e1) {
            int s[4];
            #pragma unroll
            for (int j = 0; j < 4; ++j) s[j] = csr[e + j];
            uint4 v[4]; float dv[4];
            #pragma unroll
            for (int j = 0; j < 4; ++j) { v[j] = Y[(size_t)s[j] * 16 + cl]; dv[j] = dis[s[j]]; }
            #pragma unroll
            for (int j = 0; j < 4; ++j) fma8(acc[j], v[j], dv[j]);
            e += 4;
        }
        for (; e < e1; ++e) {
            int s = csr[e];
            fma8(acc[0], Y[(size_t)s * 16 + cl], dis[s]);
        }
        float s8[8];
        #pragma unroll
        for (int k = 0; k < 8; ++k)
            s8[k] = (acc[0][k] + acc[1][k]) + (acc[2][k] + acc[3][k]);
        float4 b0 = ((const float4*)bias)[2 * cl];
        float4 b1 = ((const float4*)bias)[2 * cl + 1];
        float o[8];
        o[0] = fmaxf(dn * s8[0] + b0.x, 0.f);
        o[1] = fmaxf(dn * s8[1] + b0.y, 0.f);
        o[2] = fmaxf(dn * s8[2] + b0.z, 0.f);
        o[3] = fmaxf(dn * s8[3] + b0.w, 0.f);
        o[4] = fmaxf(dn * s8[4] + b1.x, 0.f);
        o[5] = fmaxf(dn * s8[5] + b1.y, 0.f);
        o[6] = fmaxf(dn * s8[6] + b1.z, 0.f);
        o[7] = fmaxf(dn * s8[7] + b1.w, 0.f);
        if (FINAL) {
            Of[(size_t)node * 32 + 2 * cl]     = make_float4(o[0], o[1], o[2], o[3]);
            Of[(size_t)node * 32 + 2 * cl + 1] = make_float4(o[4], o[5], o[6], o[7]);
        } else {
            bf16 t[8];
            #pragma unroll
            for (int k = 0; k < 8; ++k) t[k] = __float2bfloat16(o[k]);
            Hb[(size_t)node * 16 + cl] = *(const uint4*)t;
        }
    }
}

// ============================ init: barrier state ===========================
__global__ void init_kernel(int* __restrict__ misc) {
    if (threadIdx.x < 8) misc[threadIdx.x] = 0;
}

// ============================ mega kernel ===================================
__global__ __launch_bounds__(256, 4) void mega(MArgs a) {
    __shared__ int smem[1536];
    const int G = gridDim.x;
    const int tid = threadIdx.x;
    const int gtid = blockIdx.x * 256 + tid;
    const int gsize = G * 256;
    const int wid = tid >> 6, lane = tid & 63;
    int* bar_cnt = a.misc + 0;
    int* bar_gen = a.misc + 1;

    // ---- PA: zero bcnt; swizzle W; detect flagI (block 16) -----------------
    for (int i = gtid; i <= a.nbuck; i += gsize) a.bcnt[i] = 0;
    if (gtid < 4096) {
        // W f32 -> bf16 B-frag order: frag f=kt*8+nt; lane l: n=l&15, k=(l>>4)*8+j
        const float* W = (gtid < 2048) ? a.W1 : a.W2;
        bf16* Wsw = (gtid < 2048) ? a.Wsw1 : a.Wsw2;
        int t = gtid & 2047;
        int f = t >> 6, l = t & 63;
        int kt = f >> 3, nt = f & 7;
        int q = l >> 4, m = l & 15;
        bf16 tmp[8];
        #pragma unroll
        for (int j = 0; j < 8; ++j)
            tmp[j] = __float2bfloat16(W[(size_t)(kt * 32 + q * 8 + j) * DIM + nt * 16 + m]);
        *(bf16x8*)(Wsw + (size_t)t * 8) = *(const bf16x8*)tmp;
    }
    if (blockIdx.x == 16) {
        if (tid == 0) smem[0] = 0;
        __syncthreads();
        int lim = a.E < 16384 ? a.E : 16384;
        int acc = 0;
        for (int j = tid; j < lim; j += 256) acc |= a.ei[2 * j + 1];
        if (acc) atomicOr(&smem[0], 1);
        __syncthreads();
        if (tid == 0)
            __hip_atomic_store(&a.misc[2], smem[0], __ATOMIC_RELAXED, __HIP_MEMORY_SCOPE_AGENT);
    }
    grid_barrier(bar_cnt, bar_gen);
    const int flagI = __hip_atomic_load(&a.misc[2], __ATOMIC_RELAXED, __HIP_MEMORY_SCOPE_AGENT);

    // ---- PB: bucket count (grid-stride chunks), then gemm1 (independent) ---
    for (int c = blockIdx.x; c < a.nchunks; c += G) {
        for (int i = tid; i < a.nbuck; i += 256) smem[i] = 0;
        __syncthreads();
        int c0 = c * CHUNK;
        int cn = min(a.E - c0, CHUNK);
        for (int i = tid; i < cn; i += 256) {
            int e = c0 + i;
            int d = (flagI == 0) ? a.ei[2 * a.E + 2 * e] : a.ei[a.E + e];
            atomicAdd(&smem[d >> 7], 1);
        }
        __syncthreads();
        for (int i = tid; i < a.nbuck; i += 256)
            if (smem[i]) atomicAdd(&a.bcnt[i], smem[i]);
        __syncthreads();
    }
    gemm_body<true>(a.x, a.Wsw1, a.ybuf, a.N, blockIdx.x * 4 + wid, G * 4, lane);
    grid_barrier(bar_cnt, bar_gen);

    // ---- PC: bucket scan (block 0) -----------------------------------------
    if (blockIdx.x == 0) {
        for (int i = tid; i < a.nbuck; i += 256) smem[i] = a.bcnt[i];
        __syncthreads();
        if (tid == 0) {
            int run = 0;
            for (int i = 0; i < a.nbuck; ++i) { int v = smem[i]; smem[i] = run; run += v; }
        }
        __syncthreads();
        for (int i = tid; i < a.nbuck; i += 256) {
            a.bstart[i] = smem[i];
            a.bcursor[i] = smem[i];
        }
        if (tid == 0) a.bstart[a.nbuck] = a.E;
    }
    grid_barrier(bar_cnt, bar_gen);

    // ---- PD: bucket scatter (grid-stride chunks) ---------------------------
    {
        int* s_cnt = smem; int* s_base = smem + 512; int* s_fill = smem + 1024;
        for (int c = blockIdx.x; c < a.nchunks; c += G) {
            for (int i = tid; i < a.nbuck; i += 256) { s_cnt[i] = 0; s_fill[i] = 0; }
            __syncthreads();
            int c0 = c * CHUNK;
            int cn = min(a.E - c0, CHUNK);
            for (int i = tid; i < cn; i += 256) {
                int e = c0 + i;
                int d = (flagI == 0) ? a.ei[2 * a.E + 2 * e] : a.ei[a.E + e];
                atomicAdd(&s_cnt[d >> 7], 1);
            }
            __syncthreads();
            for (int i = tid; i < a.nbuck; i += 256) {
                int cc = s_cnt[i];
                s_base[i] = cc ? atomicAdd(&a.bcursor[i], cc) : 0;
            }
            __syncthreads();
            for (int i = tid; i < cn; i += 256) {
                int e = c0 + i;
                int s, d;
                if (flagI == 0) { s = a.ei[2 * e]; d = a.ei[2 * a.E + 2 * e]; }
                else            { s = a.ei[e];     d = a.ei[a.E + e]; }
                int b = d >> 7;
                int r = atomicAdd(&s_fill[b], 1);
                a.staged[s_base[b] + r] = ((unsigned)s << 7) | (unsigned)(d & 127);
            }
            __syncthreads();
        }
    }
    grid_barrier(bar_cnt, bar_gen);

    // ---- PE: within-bucket counting sort (grid-stride buckets) -------------
    {
        int* s_cnt = smem; int* s_off = smem + 128; int* s_fill = smem + 256;
        int* s_scan = smem + 384;
        for (int b = blockIdx.x; b < a.nbuck; b += G) {
            int seg0 = a.bstart[b], seg1 = a.bstart[b + 1];
            int n = seg1 - seg0;
            if (tid < 128) { s_cnt[tid] = 0; s_fill[tid] = 0; }
            __syncthreads();
            for (int i = tid; i < n; i += 256)
                atomicAdd(&s_cnt[a.staged[seg0 + i] & 127u], 1);
            __syncthreads();
            int v = (tid < 128) ? s_cnt[tid] : 0;
            if (tid < 128) s_scan[tid] = v;
            __syncthreads();
            for (int off = 1; off < 128; off <<= 1) {
                int t = (tid < 128 && tid >= off) ? s_scan[tid - off] : 0;
                __syncthreads();
                if (tid < 128) s_scan[tid] += t;
                __syncthreads();
            }
            if (tid < 128) {
                s_off[tid] = s_scan[tid] - v;
                int node = b * 128 + tid;
                if (node < a.N) {
                    a.cnt[node] = v;
                    a.rowstart[node] = seg0 + s_off[tid];
                    a.dis[node] = rsqrtf((float)(v + 1));   // +1 self loop
                }
            }
            __syncthreads();
            for (int i = tid; i < n; i += 256) {
                unsigned p = a.staged[seg0 + i];
                int dl = p & 127u;
                int r = atomicAdd(&s_fill[dl], 1);
                a.csr[seg0 + s_off[dl] + r] = (int)(p >> 7);
            }
            __syncthreads();
        }
    }
    grid_barrier(bar_cnt, bar_gen);

    // ---- PF: aggregate 1 -> hbuf (bf16) ------------------------------------
    {
        int sub = lane >> 4, cl = lane & 15;
        int qw = (blockIdx.x * 4 + wid) * 4 + sub;
        agg_body<false>((const uint4*)a.ybuf, a.rowstart, a.cnt, a.csr, a.dis,
                        a.b1, (uint4*)a.hbuf, nullptr, a.N, qw, G * 16, cl);
    }
    grid_barrier(bar_cnt, bar_gen);

    // ---- PG: gemm2 -> ybuf --------------------------------------------------
    gemm_body<false>(a.hbuf, a.Wsw2, a.ybuf, a.N, blockIdx.x * 4 + wid, G * 4, lane);
    grid_barrier(bar_cnt, bar_gen);

    // ---- PH: aggregate 2 -> out (f32) --------------------------------------
    {
        int sub = lane >> 4, cl = lane & 15;
        int qw = (blockIdx.x * 4 + wid) * 4 + sub;
        agg_body<true>((const uint4*)a.ybuf, a.rowstart, a.cnt, a.csr, a.dis,
                       a.b2, nullptr, a.out, a.N, qw, G * 16, cl);
    }
}

// ============================ launcher ======================================
extern "C" void kernel_launch(void* const* d_in, const int* in_sizes, int n_in,
                              void* d_out, int out_size, void* d_ws, size_t ws_size,
                              hipStream_t stream) {
    MArgs a;
    a.x  = (const float*)d_in[0];
    a.ei = (const int*)d_in[1];
    a.W1 = (const float*)d_in[2];
    a.b1 = (const float*)d_in[3];
    a.W2 = (const float*)d_in[4];
    a.b2 = (const float*)d_in[5];
    a.out = (float4*)d_out;
    a.N = in_sizes[0] / DIM;        // 50000
    a.E = in_sizes[1] / 2;          // 600000
    a.nbuck = (a.N + 127) / 128;    // 391
    a.nchunks = (a.E + CHUNK - 1) / CHUNK;  // 74

    char* w = (char*)d_ws;
    size_t used = 0;
    auto carve = [&](size_t bytes) {
        char* p = w + used;
        used += (bytes + 255) & ~(size_t)255;
        return p;
    };
    a.misc     = (int*)     carve(256);
    a.bcnt     = (int*)     carve((size_t)(a.nbuck + 1) * 4);
    a.bstart   = (int*)     carve((size_t)(a.nbuck + 1) * 4);
    a.bcursor  = (int*)     carve((size_t)a.nbuck * 4);
    a.staged   = (unsigned*)carve((size_t)a.E * 4);
    a.csr      = (int*)     carve((size_t)a.E * 4);
    a.rowstart = (int*)     carve((size_t)a.N * 4);
    a.cnt      = (int*)     carve((size_t)a.N * 4);
    a.dis      = (float*)   carve((size_t)a.N * 4);
    a.ybuf     = (bf16*)    carve((size_t)a.N * DIM * 2);
    a.hbuf     = (bf16*)    carve((size_t)a.N * DIM * 2);
    a.Wsw1     = (bf16*)    carve((size_t)DIM * DIM * 2);
    a.Wsw2     = (bf16*)    carve((size_t)DIM * DIM * 2);

    // Grid sized to guaranteed co-residency (pure host queries; capture-safe,
    // deterministic -> same work every call).
    int dev = 0;
    (void)hipGetDevice(&dev);
    int cus = 0;
    (void)hipDeviceGetAttribute(&cus, hipDeviceAttributeMultiprocessorCount, dev);
    if (cus <= 0) cus = 256;
    int maxB = 0;
    (void)hipOccupancyMaxActiveBlocksPerMultiprocessor(&maxB, mega, 256, 0);
    if (maxB <= 0) maxB = 1;
    long grid = (long)maxB * cus;
    if (grid > 1024) grid = 1024;
    if (grid < 64) grid = 64;

    init_kernel<<<1, 64, 0, stream>>>(a.misc);
    mega<<<(int)grid, 256, 0, stream>>>(a);
}

// Round 15
// 230.384 us; speedup vs baseline: 4.9117x; 2.3418x over previous
//
#include <hip/hip_runtime.h>
#include <hip/hip_bf16.h>

#define DIM 128
#define CHUNK 8192
#define CAP 4096        // slab capacity per 128-node bucket (65 sigma above mean)
typedef __hip_bfloat16 bf16;
typedef __attribute__((ext_vector_type(8))) short bf16x8;   // 8 bf16 = 4 VGPRs
typedef __attribute__((ext_vector_type(4))) float f32x4;

// ============================ K1: prep ======================================
// b0: init slab cursors; b1: int-width detect (flagI: 0 -> int64); b2..17: W swizzle
__global__ void prep_kernel(int* __restrict__ bcursor, int nbuck,
                            const int* __restrict__ ei, int E, int* __restrict__ misc,
                            const float* __restrict__ W1, const float* __restrict__ W2,
                            bf16* __restrict__ Wsw1, bf16* __restrict__ Wsw2) {
    if (blockIdx.x == 0) {
        for (int i = threadIdx.x; i < nbuck; i += 256) bcursor[i] = i * CAP;
    } else if (blockIdx.x == 1) {
        __shared__ int s_or;
        if (threadIdx.x == 0) s_or = 0;
        __syncthreads();
        int lim = E < 16384 ? E : 16384;
        int acc = 0;
        for (int j = threadIdx.x; j < lim; j += 256) acc |= ei[2 * j + 1];
        if (acc) atomicOr(&s_or, 1);
        __syncthreads();
        if (threadIdx.x == 0) misc[1] = s_or;
    } else {
        // W f32 -> bf16 B-fragment order: frag f=kt*8+nt, lane l: n=l&15, k=(l>>4)*8+j
        int id = (blockIdx.x - 2) * 256 + threadIdx.x;       // 0..4095
        const float* W = (id < 2048) ? W1 : W2;
        bf16* Wsw = (id < 2048) ? Wsw1 : Wsw2;
        int t = id & 2047;
        int f = t >> 6, l = t & 63;
        int kt = f >> 3, nt = f & 7;
        int q = l >> 4, m = l & 15;
        bf16 tmp[8];
        #pragma unroll
        for (int j = 0; j < 8; ++j)
            tmp[j] = __float2bfloat16(W[(size_t)(kt * 32 + q * 8 + j) * DIM + nt * 16 + m]);
        *(bf16x8*)(Wsw + (size_t)t * 8) = *(const bf16x8*)tmp;
    }
}

// ============================ K2: slab scatter ==============================
// packed (src<<7 | dst&127) into per-(block,bucket) runs inside fixed slabs
__global__ void slab_scatter(const int* __restrict__ ei, int E,
                             const int* __restrict__ misc,
                             int* __restrict__ bcursor,
                             unsigned* __restrict__ staged, int nbuck) {
    __shared__ int s_cnt[512], s_base[512], s_fill[512];
    for (int i = threadIdx.x; i < nbuck; i += 512) { s_cnt[i] = 0; s_fill[i] = 0; }
    __syncthreads();
    int flagI = misc[1];
    int c0 = blockIdx.x * CHUNK;
    int cn = min(E - c0, CHUNK);
    for (int i = threadIdx.x; i < cn; i += 512) {
        int e = c0 + i;
        int d = (flagI == 0) ? ei[2 * E + 2 * e] : ei[E + e];
        atomicAdd(&s_cnt[d >> 7], 1);
    }
    __syncthreads();
    for (int i = threadIdx.x; i < nbuck; i += 512) {
        int c = s_cnt[i];
        s_base[i] = c ? atomicAdd(&bcursor[i], c) : 0;
    }
    __syncthreads();
    for (int i = threadIdx.x; i < cn; i += 512) {
        int e = c0 + i;
        int s, d;
        if (flagI == 0) { s = ei[2 * e]; d = ei[2 * E + 2 * e]; }
        else            { s = ei[e];     d = ei[E + e]; }
        int b = d >> 7;
        int r = s_base[b] + atomicAdd(&s_fill[b], 1);
        if (r < (b + 1) * CAP)                           // overflow clamp (never hit)
            staged[r] = ((unsigned)s << 7) | (unsigned)(d & 127);
    }
}

// ============================ K3: within-bucket sort ========================
// block per bucket: counting sort staged slab -> csr slab; emits rowstart/cnt/dis
__global__ void bucket_sort(const unsigned* __restrict__ staged,
                            const int* __restrict__ bcursor,
                            int* __restrict__ csr, int* __restrict__ rowstart,
                            int* __restrict__ cnt, float* __restrict__ dis, int N) {
    __shared__ int s_cnt[128], s_off[128], s_fill[128], s_scan[128];
    int b = blockIdx.x, tid = threadIdx.x;
    int seg0 = b * CAP;
    int n = min(bcursor[b] - seg0, CAP);
    if (tid < 128) { s_cnt[tid] = 0; s_fill[tid] = 0; }
    __syncthreads();
    for (int i = tid; i < n; i += 256)
        atomicAdd(&s_cnt[staged[seg0 + i] & 127u], 1);
    __syncthreads();
    int v = (tid < 128) ? s_cnt[tid] : 0;
    if (tid < 128) s_scan[tid] = v;
    __syncthreads();
    for (int off = 1; off < 128; off <<= 1) {
        int t = (tid < 128 && tid >= off) ? s_scan[tid - off] : 0;
        __syncthreads();
        if (tid < 128) s_scan[tid] += t;
        __syncthreads();
    }
    if (tid < 128) {
        s_off[tid] = s_scan[tid] - v;
        int node = b * 128 + tid;
        if (node < N) {
            cnt[node] = v;
            rowstart[node] = seg0 + s_off[tid];
            dis[node] = rsqrtf((float)(v + 1));   // +1 self loop
        }
    }
    __syncthreads();
    for (int i = tid; i < n; i += 256) {
        unsigned p = staged[seg0 + i];
        int dl = p & 127u;
        int r = atomicAdd(&s_fill[dl], 1);
        csr[seg0 + s_off[dl] + r] = (int)(p >> 7);
    }
}

// ============================ MFMA gemm (UNSCALED) ==========================
// Y[node][c] = bf16(X[node,:] @ W[:,c]); wave = 16 nodes x 128 cols
template <bool XF32>
__device__ __forceinline__ void gemm_body(const void* __restrict__ Xv,
                                          const bf16* __restrict__ Wsw,
                                          bf16* __restrict__ Y, int N,
                                          int gw, int nw, int lane) {
    int m = lane & 15, q = lane >> 4;
    const bf16x8* bp = (const bf16x8*)Wsw;          // frag f at bp[f*64 + lane]
    for (int t = gw; t * 16 + 16 <= N; t += nw) {
        int base = t * 16;
        bf16x8 a[4];
        if (XF32) {
            const float* xp = (const float*)Xv + (size_t)(base + m) * DIM + q * 8;
            #pragma unroll
            for (int kt = 0; kt < 4; ++kt) {
                float4 v0 = *(const float4*)(xp + kt * 32);
                float4 v1 = *(const float4*)(xp + kt * 32 + 4);
                bf16 tt[8] = {__float2bfloat16(v0.x), __float2bfloat16(v0.y),
                              __float2bfloat16(v0.z), __float2bfloat16(v0.w),
                              __float2bfloat16(v1.x), __float2bfloat16(v1.y),
                              __float2bfloat16(v1.z), __float2bfloat16(v1.w)};
                a[kt] = *(const bf16x8*)tt;
            }
        } else {
            const bf16* xp = (const bf16*)Xv + (size_t)(base + m) * DIM + q * 8;
            #pragma unroll
            for (int kt = 0; kt < 4; ++kt)
                a[kt] = *(const bf16x8*)(xp + kt * 32);
        }
        f32x4 acc[8];
        #pragma unroll
        for (int nt = 0; nt < 8; ++nt) acc[nt] = (f32x4){0.f, 0.f, 0.f, 0.f};
        #pragma unroll
        for (int kt = 0; kt < 4; ++kt) {
            #pragma unroll
            for (int nt = 0; nt < 8; ++nt) {
                bf16x8 bfr = bp[(size_t)(kt * 8 + nt) * 64 + lane];
                acc[nt] = __builtin_amdgcn_mfma_f32_16x16x32_bf16(a[kt], bfr, acc[nt], 0, 0, 0);
            }
        }
        // D: row (node) = q*4 + r, col (channel) = nt*16 + m  [m89/m91-verified]
        #pragma unroll
        for (int nt = 0; nt < 8; ++nt)
            #pragma unroll
            for (int r = 0; r < 4; ++r)
                Y[(size_t)(base + q * 4 + r) * DIM + nt * 16 + m] =
                    __float2bfloat16(acc[nt][r]);
    }
}

__global__ void gemm1(const float* __restrict__ X, const bf16* __restrict__ Wsw,
                      bf16* __restrict__ Y, int N) {
    int wid = threadIdx.x >> 6, lane = threadIdx.x & 63;
    gemm_body<true>(X, Wsw, Y, N, blockIdx.x * 4 + wid, gridDim.x * 4, lane);
}

__global__ void gemm2(const bf16* __restrict__ H, const bf16* __restrict__ Wsw,
                      bf16* __restrict__ Y, int N) {
    int wid = threadIdx.x >> 6, lane = threadIdx.x & 63;
    gemm_body<false>(H, Wsw, Y, N, blockIdx.x * 4 + wid, gridDim.x * 4, lane);
}

// ============================ aggregate =====================================
// out[n][c] = relu(dis[n]*(y[n][c]*dis[n] + sum_src y[src][c]*dis[src]) + b[c])
// Quarter-wave (16 lanes) per node; lane covers 8 channels via one uint4.
__device__ __forceinline__ void fma8(float* a, uint4 v, float ds) {
    a[0] = fmaf(__uint_as_float(v.x << 16), ds, a[0]);
    a[1] = fmaf(__uint_as_float(v.x & 0xffff0000u), ds, a[1]);
    a[2] = fmaf(__uint_as_float(v.y << 16), ds, a[2]);
    a[3] = fmaf(__uint_as_float(v.y & 0xffff0000u), ds, a[3]);
    a[4] = fmaf(__uint_as_float(v.z << 16), ds, a[4]);
    a[5] = fmaf(__uint_as_float(v.z & 0xffff0000u), ds, a[5]);
    a[6] = fmaf(__uint_as_float(v.w << 16), ds, a[6]);
    a[7] = fmaf(__uint_as_float(v.w & 0xffff0000u), ds, a[7]);
}

template <bool FINAL>
__global__ __launch_bounds__(256, 4)
void aggregate_bf(const uint4* __restrict__ Y, const int* __restrict__ rowstart,
                  const int* __restrict__ cnt, const int* __restrict__ csr,
                  const float* __restrict__ dis, const float* __restrict__ bias,
                  uint4* __restrict__ Hb, float4* __restrict__ Of, int N) {
    int wave = threadIdx.x >> 6;
    int lane = threadIdx.x & 63;
    int sub = lane >> 4, cl = lane & 15;        // node-in-wave, uint4 index in row
    int node = blockIdx.x * 16 + wave * 4 + sub;
    if (node >= N) return;
    int e0 = rowstart[node], e1 = e0 + cnt[node];

    float acc[4][8];
    #pragma unroll
    for (int j = 0; j < 4; ++j)
        #pragma unroll
        for (int k = 0; k < 8; ++k) acc[j][k] = 0.f;

    float dn = dis[node];
    fma8(acc[3], Y[(size_t)node * 16 + cl], dn);        // self loop

    int e = e0;
    while (e + 8 <= e1) {
        int s[8];
        #pragma unroll
        for (int j = 0; j < 8; ++j) s[j] = csr[e + j];
        uint4 v[8]; float dv[8];
        #pragma unroll
        for (int j = 0; j < 8; ++j) { v[j] = Y[(size_t)s[j] * 16 + cl]; dv[j] = dis[s[j]]; }
        #pragma unroll
        for (int j = 0; j < 8; ++j) fma8(acc[j & 3], v[j], dv[j]);
        e += 8;
    }
    if (e + 4 <= e1) {
        int s[4];
        #pragma unroll
        for (int j = 0; j < 4; ++j) s[j] = csr[e + j];
        uint4 v[4]; float dv[4];
        #pragma unroll
        for (int j = 0; j < 4; ++j) { v[j] = Y[(size_t)s[j] * 16 + cl]; dv[j] = dis[s[j]]; }
        #pragma unroll
        for (int j = 0; j < 4; ++j) fma8(acc[j], v[j], dv[j]);
        e += 4;
    }
    for (; e < e1; ++e) {
        int s = csr[e];
        fma8(acc[0], Y[(size_t)s * 16 + cl], dis[s]);
    }

    float s8[8];
    #pragma unroll
    for (int k = 0; k < 8; ++k)
        s8[k] = (acc[0][k] + acc[1][k]) + (acc[2][k] + acc[3][k]);

    float4 b0 = ((const float4*)bias)[2 * cl];
    float4 b1 = ((const float4*)bias)[2 * cl + 1];
    float o[8];
    o[0] = fmaxf(dn * s8[0] + b0.x, 0.f);
    o[1] = fmaxf(dn * s8[1] + b0.y, 0.f);
    o[2] = fmaxf(dn * s8[2] + b0.z, 0.f);
    o[3] = fmaxf(dn * s8[3] + b0.w, 0.f);
    o[4] = fmaxf(dn * s8[4] + b1.x, 0.f);
    o[5] = fmaxf(dn * s8[5] + b1.y, 0.f);
    o[6] = fmaxf(dn * s8[6] + b1.z, 0.f);
    o[7] = fmaxf(dn * s8[7] + b1.w, 0.f);
    if (FINAL) {
        Of[(size_t)node * 32 + 2 * cl]     = make_float4(o[0], o[1], o[2], o[3]);
        Of[(size_t)node * 32 + 2 * cl + 1] = make_float4(o[4], o[5], o[6], o[7]);
    } else {
        bf16 t[8];
        #pragma unroll
        for (int k = 0; k < 8; ++k) t[k] = __float2bfloat16(o[k]);
        Hb[(size_t)node * 16 + cl] = *(const uint4*)t;
    }
}

// ============================ launcher ======================================
extern "C" void kernel_launch(void* const* d_in, const int* in_sizes, int n_in,
                              void* d_out, int out_size, void* d_ws, size_t ws_size,
                              hipStream_t stream) {
    const float* x  = (const float*)d_in[0];
    const int*   ei = (const int*)d_in[1];
    const float* W1 = (const float*)d_in[2];
    const float* b1 = (const float*)d_in[3];
    const float* W2 = (const float*)d_in[4];
    const float* b2 = (const float*)d_in[5];

    int N = in_sizes[0] / DIM;      // 50000
    int E = in_sizes[1] / 2;        // 600000
    int nbuck = (N + 127) / 128;    // 391
    int nchunks = (E + CHUNK - 1) / CHUNK;  // 74

    char* w = (char*)d_ws;
    size_t used = 0;
    auto carve = [&](size_t bytes) {
        char* p = w + used;
        used += (bytes + 255) & ~(size_t)255;
        return p;
    };
    int*      misc     = (int*)     carve(256);              // [1]=flagI
    int*      bcursor  = (int*)     carve((size_t)(nbuck + 1) * 4);
    unsigned* staged   = (unsigned*)carve((size_t)nbuck * CAP * 4);   // 6.4 MB
    int*      csr      = (int*)     carve((size_t)nbuck * CAP * 4);   // 6.4 MB
    int*      rowstart = (int*)     carve((size_t)N * 4);
    int*      cnt      = (int*)     carve((size_t)N * 4);
    float*    dis      = (float*)   carve((size_t)N * 4);
    bf16*     ybuf     = (bf16*)    carve((size_t)N * DIM * 2);
    bf16*     hbuf     = (bf16*)    carve((size_t)N * DIM * 2);
    bf16*     Wsw1     = (bf16*)    carve((size_t)DIM * DIM * 2);
    bf16*     Wsw2     = (bf16*)    carve((size_t)DIM * DIM * 2);

    prep_kernel <<<18, 256, 0, stream>>>(bcursor, nbuck, ei, E, misc, W1, W2, Wsw1, Wsw2);
    slab_scatter<<<nchunks, 512, 0, stream>>>(ei, E, misc, bcursor, staged, nbuck);
    bucket_sort <<<nbuck, 256, 0, stream>>>(staged, bcursor, csr, rowstart, cnt, dis, N);

    int ablocks = (N + 15) / 16;            // 3125
    gemm1<<<784, 256, 0, stream>>>(x, Wsw1, ybuf, N);
    aggregate_bf<false><<<ablocks, 256, 0, stream>>>((const uint4*)ybuf, rowstart, cnt,
                                                     csr, dis, b1, (uint4*)hbuf, nullptr, N);
    gemm2<<<784, 256, 0, stream>>>(hbuf, Wsw2, ybuf, N);
    aggregate_bf<true><<<ablocks, 256, 0, stream>>>((const uint4*)ybuf, rowstart, cnt,
                                                    csr, dis, b2, nullptr, (float4*)d_out, N);
}